// Round 1
// baseline (37558.417 us; speedup 1.0000x reference)
//
#include <hip/hip_runtime.h>
#include <stdint.h>

#define TLEN 1024
#define BATCH 64
#define DIMX 128
#define HID 512
#define BB 8      // batch rows per group
#define SLC 16    // h-columns per WG

typedef __attribute__((ext_vector_type(8))) short short8;
typedef __attribute__((ext_vector_type(4))) float f32x4;

// ---- workspace layout (bytes) ----
#define OFF_WT   0u           // Wt: [2048][640] bf16 = 2,621,440
#define OFF_XBF  2621440u     // xbf: [64][1024][128] bf16 = 16,777,216
#define OFF_HB   19398656u    // hb: [3][64][512] bf16 = 196,608
#define OFF_FLG  19595264u    // flags: [8][32] u32 = 1,024
#define OFF_ACC  19596288u    // acc: 16
#define ZERO_LEN (196608u + 1024u + 16u)

__device__ __forceinline__ unsigned short f2bf(float f) {
  unsigned u = __float_as_uint(f);
  u += 0x7fffu + ((u >> 16) & 1u);
  return (unsigned short)(u >> 16);
}
__device__ __forceinline__ float bf2f(unsigned short h) {
  return __uint_as_float(((unsigned)h) << 16);
}
__device__ __forceinline__ float sigm(float x) { return 1.0f / (1.0f + __expf(-x)); }
__device__ __forceinline__ float tanh_fast(float x) {
  float a = fabsf(x);
  float e = __expf(2.0f * a);
  float t = 1.0f - 2.0f / (e + 1.0f);
  return copysignf(t, x);
}

// ---- x fp32 -> bf16, coalesced ----
__global__ void k_convx(const float4* __restrict__ x4, ushort4* __restrict__ o4) {
  int i = blockIdx.x * 256 + threadIdx.x;
  float4 v = x4[i];
  ushort4 o;
  o.x = f2bf(v.x); o.y = f2bf(v.y); o.z = f2bf(v.z); o.w = f2bf(v.w);
  o4[i] = o;
}

// ---- build Wt[col 0..2047][k 0..639] bf16 = concat(Wx;Wh)^T, LDS-tiled transpose ----
__global__ void k_tw(const float* __restrict__ Wx, const float* __restrict__ Wh,
                     unsigned short* __restrict__ Wt) {
  __shared__ float tile[32][65];
  int bk = blockIdx.x;
  int k0 = (bk / 64) * 64;       // 0..576 (multiple of 64, never straddles 128)
  int c0 = (bk % 64) * 32;
  int tid = threadIdx.x;
  const float* src = (k0 < 128) ? (Wx + (size_t)k0 * 2048)
                                : (Wh + (size_t)(k0 - 128) * 2048);
#pragma unroll
  for (int p = 0; p < 8; ++p) {
    int i = p * 256 + tid;
    int kk = i >> 5, cc = i & 31;
    tile[cc][kk] = src[(size_t)kk * 2048 + (c0 + cc)];
  }
  __syncthreads();
  int cc = tid >> 3, ch = tid & 7;
  unsigned short tmp[8];
#pragma unroll
  for (int j = 0; j < 8; ++j) tmp[j] = f2bf(tile[cc][ch * 8 + j]);
  uint4 o;
  o.x = (unsigned)tmp[0] | ((unsigned)tmp[1] << 16);
  o.y = (unsigned)tmp[2] | ((unsigned)tmp[3] << 16);
  o.z = (unsigned)tmp[4] | ((unsigned)tmp[5] << 16);
  o.w = (unsigned)tmp[6] | ((unsigned)tmp[7] << 16);
  *(uint4*)(Wt + (size_t)(c0 + cc) * 640 + k0 + ch * 8) = o;
}

// ---- persistent recurrence kernel: 256 WGs = 8 groups x 32 slice-WGs ----
__global__ __launch_bounds__(256, 1) void k_lstm(
    const unsigned short* __restrict__ xbf,   // [B][T][D]
    const unsigned short* __restrict__ Wt,    // [4H][640] (B^T layout)
    const float* __restrict__ bias,           // [4H]
    const float* __restrict__ Wo,             // [H][2]
    const float* __restrict__ bo,             // [2]
    const int* __restrict__ labels,           // [B][T]
    unsigned short* __restrict__ hb,          // [3][B][H]
    unsigned int* __restrict__ flags,         // [8][32]
    float* __restrict__ acc,                  // [1]
    float* __restrict__ out)                  // [B][T][2] (+cost slot, written later)
{
  __shared__ float red[4 * 4 * 8 * 16];   // [wave][gate][row<8][col16]
  __shared__ float part[BB * 16 * 2];     // logits partials

  const int tid  = threadIdx.x;
  const int w    = tid >> 6;      // wave 0..3 (K-split)
  const int lane = tid & 63;
  const int q    = lane >> 4;
  const int m    = lane & 15;
  const int grp  = blockIdx.x & 7;   // group -> (heuristically) XCD
  const int hj   = blockIdx.x >> 3;  // slice 0..31
  const int g0   = grp * BB;

  // ---- pin B fragments (weight slice) in registers: Bf[kk][gate] ----
  short8 Bf[5][4];
  {
    const int kbase = w * 160;
#pragma unroll
    for (int kk = 0; kk < 5; ++kk) {
#pragma unroll
      for (int G = 0; G < 4; ++G) {
        int col = G * HID + hj * SLC + m;
        int k = kbase + kk * 32 + q * 8;
        Bf[kk][G] = *(const short8*)(Wt + (size_t)col * 640 + k);
      }
    }
  }

  // gate-thread state (tid<128 owns (row=tid>>4, ch=tid&15))
  const int grow = tid >> 4;
  const int gch  = tid & 15;
  float c_state = 0.0f;
  float b_i = 0, b_f = 0, b_g = 0, b_o = 0;
  if (tid < 128) {
    int col = hj * SLC + gch;
    b_i = bias[0 * HID + col];
    b_f = bias[1 * HID + col];
    b_g = bias[2 * HID + col];
    b_o = bias[3 * HID + col];
  }

  const int arow = (m < BB) ? m : (BB - 1);   // clamp pad rows (rows 8..15 unused)
  const size_t ab = (size_t)(g0 + arow);
  unsigned int* myflags = flags + grp * 32;
  float nll_part = 0.0f;

  int slot_cur = 0;   // h_{t-1} lives in slot t%3
#pragma unroll 1
  for (int t = 0; t < TLEN; ++t) {
    int slot_nxt = slot_cur + 1; if (slot_nxt == 3) slot_nxt = 0;

    // ---- A fragments: concat(x_t, h_{t-1}) rows=batch ----
    short8 a[5];
#pragma unroll
    for (int kk = 0; kk < 5; ++kk) {
      int k = w * 160 + kk * 32 + q * 8;
      const unsigned short* p;
      if (k < 128) p = xbf + (ab * TLEN + (size_t)t) * DIMX + k;
      else         p = hb + (size_t)slot_cur * (BATCH * HID) + ab * HID + (k - 128);
      a[kk] = *(const short8*)p;
    }

    // ---- MFMA: z-slice partials over this wave's K-range ----
    f32x4 z0 = {0,0,0,0}, z1 = {0,0,0,0}, z2 = {0,0,0,0}, z3 = {0,0,0,0};
#pragma unroll
    for (int kk = 0; kk < 5; ++kk) {
      z0 = __builtin_amdgcn_mfma_f32_16x16x32_bf16(a[kk], Bf[kk][0], z0, 0, 0, 0);
      z1 = __builtin_amdgcn_mfma_f32_16x16x32_bf16(a[kk], Bf[kk][1], z1, 0, 0, 0);
      z2 = __builtin_amdgcn_mfma_f32_16x16x32_bf16(a[kk], Bf[kk][2], z2, 0, 0, 0);
      z3 = __builtin_amdgcn_mfma_f32_16x16x32_bf16(a[kk], Bf[kk][3], z3, 0, 0, 0);
    }

    // ---- cross-wave reduce staging (valid batch rows live in quads 0,1) ----
    if (q < 2) {
#pragma unroll
      for (int r = 0; r < 4; ++r) {
        int rowi = q * 4 + r;
        red[((w * 4 + 0) * 8 + rowi) * 16 + m] = z0[r];
        red[((w * 4 + 1) * 8 + rowi) * 16 + m] = z1[r];
        red[((w * 4 + 2) * 8 + rowi) * 16 + m] = z2[r];
        red[((w * 4 + 3) * 8 + rowi) * 16 + m] = z3[r];
      }
    }
    __syncthreads();

    // ---- gates + state update + h store ----
    if (tid < 128) {
      float zi = b_i, zf = b_f, zg = b_g, zo = b_o;
#pragma unroll
      for (int ww = 0; ww < 4; ++ww) {
        zi += red[((ww * 4 + 0) * 8 + grow) * 16 + gch];
        zf += red[((ww * 4 + 1) * 8 + grow) * 16 + gch];
        zg += red[((ww * 4 + 2) * 8 + grow) * 16 + gch];
        zo += red[((ww * 4 + 3) * 8 + grow) * 16 + gch];
      }
      float ig = sigm(zi), fg = sigm(zf), gg = tanh_fast(zg), og = sigm(zo);
      c_state = fg * c_state + ig * gg;
      float hval = og * tanh_fast(c_state);
      hb[(size_t)slot_nxt * (BATCH * HID) + (size_t)(g0 + grow) * HID + hj * SLC + gch] =
          f2bf(hval);
    }
    __threadfence();          // make h stores agent-visible
    __syncthreads();
    if (tid == 0)
      __hip_atomic_store(&myflags[hj], (unsigned)(t + 1), __ATOMIC_RELEASE,
                         __HIP_MEMORY_SCOPE_AGENT);

    // ---- duty (rotating WG): predictions + NLL for step t-1, hidden in others' spin ----
    if (t >= 1 && hj == (t & 31)) {
      const unsigned short* hrow = hb + (size_t)slot_cur * (BATCH * HID);
      if (tid < 128) {
        int b = tid >> 4, seg = tid & 15;
        const unsigned short* hp = hrow + (size_t)(g0 + b) * HID + seg * 32;
        float p0 = 0.0f, p1 = 0.0f;
#pragma unroll 4
        for (int j = 0; j < 32; ++j) {
          float hv = bf2f(hp[j]);
          float2 wv = ((const float2*)Wo)[seg * 32 + j];
          p0 += hv * wv.x;
          p1 += hv * wv.y;
        }
        part[(b * 16 + seg) * 2 + 0] = p0;
        part[(b * 16 + seg) * 2 + 1] = p1;
      }
      __syncthreads();
      if (tid < 8) {
        int b = tid;
        float l0 = bo[0], l1 = bo[1];
#pragma unroll
        for (int sg = 0; sg < 16; ++sg) {
          l0 += part[(b * 16 + sg) * 2 + 0];
          l1 += part[(b * 16 + sg) * 2 + 1];
        }
        int tp = t - 1;
        float mx = fmaxf(l0, l1);
        float e0 = __expf(l0 - mx), e1 = __expf(l1 - mx);
        float s = e0 + e1, inv = 1.0f / s;
        size_t base = ((size_t)(g0 + b) * TLEN + tp) * 2;
        out[base + 0] = e0 * inv;
        out[base + 1] = e1 * inv;
        int lab = labels[(size_t)(g0 + b) * TLEN + tp];
        float lsel = lab ? l1 : l0;
        nll_part += __logf(s) - (lsel - mx);
      }
    }

    // ---- group barrier: wave0 polls all 32 member flags ----
    if (tid < 64) {
      unsigned tgt = (unsigned)(t + 1);
      int guard = 0;
      for (;;) {
        unsigned v = __hip_atomic_load(&myflags[lane & 31], __ATOMIC_RELAXED,
                                       __HIP_MEMORY_SCOPE_AGENT);
        if (__ballot(v < tgt) == 0ull) break;
        if (++guard > (1 << 23)) break;   // safety: never hang forever
      }
    }
    __syncthreads();
    __threadfence();          // acquire: invalidate caches before reading fresh h
    slot_cur = slot_nxt;
  }

  // ---- tail duty: predictions for t = T-1 (h_{T-1} in slot_cur) ----
  if (hj == (TLEN & 31)) {
    const unsigned short* hrow = hb + (size_t)slot_cur * (BATCH * HID);
    if (tid < 128) {
      int b = tid >> 4, seg = tid & 15;
      const unsigned short* hp = hrow + (size_t)(g0 + b) * HID + seg * 32;
      float p0 = 0.0f, p1 = 0.0f;
#pragma unroll 4
      for (int j = 0; j < 32; ++j) {
        float hv = bf2f(hp[j]);
        float2 wv = ((const float2*)Wo)[seg * 32 + j];
        p0 += hv * wv.x;
        p1 += hv * wv.y;
      }
      part[(b * 16 + seg) * 2 + 0] = p0;
      part[(b * 16 + seg) * 2 + 1] = p1;
    }
    __syncthreads();
    if (tid < 8) {
      int b = tid;
      float l0 = bo[0], l1 = bo[1];
#pragma unroll
      for (int sg = 0; sg < 16; ++sg) {
        l0 += part[(b * 16 + sg) * 2 + 0];
        l1 += part[(b * 16 + sg) * 2 + 1];
      }
      int tp = TLEN - 1;
      float mx = fmaxf(l0, l1);
      float e0 = __expf(l0 - mx), e1 = __expf(l1 - mx);
      float s = e0 + e1, inv = 1.0f / s;
      size_t base = ((size_t)(g0 + b) * TLEN + tp) * 2;
      out[base + 0] = e0 * inv;
      out[base + 1] = e1 * inv;
      int lab = labels[(size_t)(g0 + b) * TLEN + tp];
      float lsel = lab ? l1 : l0;
      nll_part += __logf(s) - (lsel - mx);
    }
  }

  if (nll_part != 0.0f) atomicAdd(acc, nll_part);
}

__global__ void k_fin(const float* __restrict__ acc, float* __restrict__ out) {
  out[BATCH * TLEN * 2] = acc[0] * (1.0f / (float)(BATCH * TLEN));
}

extern "C" void kernel_launch(void* const* d_in, const int* in_sizes, int n_in,
                              void* d_out, int out_size, void* d_ws, size_t ws_size,
                              hipStream_t stream) {
  const float* x      = (const float*)d_in[0];
  const int*   labels = (const int*)d_in[1];
  const float* Wx     = (const float*)d_in[2];
  const float* Wh     = (const float*)d_in[3];
  const float* b      = (const float*)d_in[4];
  const float* Wo     = (const float*)d_in[5];
  const float* bo     = (const float*)d_in[6];
  float* out = (float*)d_out;
  char* ws = (char*)d_ws;

  unsigned short* Wt    = (unsigned short*)(ws + OFF_WT);
  unsigned short* xbf   = (unsigned short*)(ws + OFF_XBF);
  unsigned short* hb    = (unsigned short*)(ws + OFF_HB);
  unsigned int*   flags = (unsigned int*)(ws + OFF_FLG);
  float*          acc   = (float*)(ws + OFF_ACC);

  hipMemsetAsync(ws + OFF_HB, 0, ZERO_LEN, stream);
  k_convx<<<8192, 256, 0, stream>>>((const float4*)x, (ushort4*)xbf);
  k_tw<<<640, 256, 0, stream>>>(Wx, Wh, Wt);
  k_lstm<<<256, 256, 0, stream>>>(xbf, Wt, b, Wo, bo, labels, hb, flags, acc, out);
  k_fin<<<1, 1, 0, stream>>>(acc, out);
}

// Round 2
// 4679.047 us; speedup vs baseline: 8.0269x; 8.0269x over previous
//
#include <hip/hip_runtime.h>
#include <stdint.h>

#define TLEN 1024
#define BATCH 64
#define DIMX 128
#define HID 512

typedef __attribute__((ext_vector_type(8))) short short8;
typedef __attribute__((ext_vector_type(4))) float f32x4;

// ---- workspace layout (bytes) ----
#define OFF_WT   0u           // Wt: [2048][640] bf16 = 2,621,440
#define OFF_XBF  2621440u     // xbf: [64][1024][128] bf16 = 16,777,216
#define OFF_HB   19398656u    // hb: [2][64][512] u32 (tagged bf16) = 262,144
#define OFF_ACC  19660800u    // acc: 64

__device__ __forceinline__ unsigned short f2bf(float f) {
  unsigned u = __float_as_uint(f);
  u += 0x7fffu + ((u >> 16) & 1u);
  return (unsigned short)(u >> 16);
}
__device__ __forceinline__ float sigm(float x) { return 1.0f / (1.0f + __expf(-x)); }
__device__ __forceinline__ float tanh_fast(float x) {
  float a = fabsf(x);
  float e = __expf(2.0f * a);
  float t = 1.0f - 2.0f / (e + 1.0f);
  return copysignf(t, x);
}
__device__ __forceinline__ unsigned long long aload64(const unsigned* p) {
  return __hip_atomic_load((const unsigned long long*)p, __ATOMIC_RELAXED,
                           __HIP_MEMORY_SCOPE_AGENT);
}

// ---- x fp32 -> bf16, coalesced ----
__global__ void k_convx(const float4* __restrict__ x4, ushort4* __restrict__ o4) {
  int i = blockIdx.x * 256 + threadIdx.x;
  float4 v = x4[i];
  ushort4 o;
  o.x = f2bf(v.x); o.y = f2bf(v.y); o.z = f2bf(v.z); o.w = f2bf(v.w);
  o4[i] = o;
}

// ---- build Wt[col 0..2047][k 0..639] bf16 = concat(Wx;Wh)^T (proven in R1) ----
__global__ void k_tw(const float* __restrict__ Wx, const float* __restrict__ Wh,
                     unsigned short* __restrict__ Wt) {
  __shared__ float tile[32][65];
  int bk = blockIdx.x;
  int k0 = (bk / 64) * 64;
  int c0 = (bk % 64) * 32;
  int tid = threadIdx.x;
  const float* src = (k0 < 128) ? (Wx + (size_t)k0 * 2048)
                                : (Wh + (size_t)(k0 - 128) * 2048);
#pragma unroll
  for (int p = 0; p < 8; ++p) {
    int i = p * 256 + tid;
    int kk = i >> 5, cc = i & 31;
    tile[cc][kk] = src[(size_t)kk * 2048 + (c0 + cc)];
  }
  __syncthreads();
  int cc = tid >> 3, ch = tid & 7;
  unsigned short tmp[8];
#pragma unroll
  for (int j = 0; j < 8; ++j) tmp[j] = f2bf(tile[cc][ch * 8 + j]);
  uint4 o;
  o.x = (unsigned)tmp[0] | ((unsigned)tmp[1] << 16);
  o.y = (unsigned)tmp[2] | ((unsigned)tmp[3] << 16);
  o.z = (unsigned)tmp[4] | ((unsigned)tmp[5] << 16);
  o.w = (unsigned)tmp[6] | ((unsigned)tmp[7] << 16);
  *(uint4*)(Wt + (size_t)(c0 + cc) * 640 + k0 + ch * 8) = o;
}

// ---- recurrence: 128 WGs = 8 groups x 16 WGs(512thr). Fence-free tagged dataflow. ----
__global__ __launch_bounds__(512, 1) void k_lstm(
    const unsigned short* __restrict__ xbf,   // [B][T][D] bf16
    const unsigned short* __restrict__ Wt,    // [4H][640] bf16 (B^T layout)
    const float* __restrict__ bias,           // [4H]
    const float* __restrict__ Wo,             // [H][2]
    unsigned* __restrict__ hb,                // [2][B][H] tagged u32
    float* __restrict__ out)                  // [B][T][2] logits via atomicAdd
{
  __shared__ float red[2][4][4][8][32];  // [buf][kw][gate][row][col]

  const int tid  = threadIdx.x;
  const int w    = tid >> 6;      // wave 0..7
  const int kw   = w & 3;         // K-split: K range kw*160..+159
  const int cg   = w >> 2;        // gate pair: gates 2cg, 2cg+1
  const int lane = tid & 63;
  const int q    = lane >> 4;
  const int m    = lane & 15;
  const int grp  = blockIdx.x & 7;   // group (8 batch rows)
  const int hw   = blockIdx.x >> 3;  // h-col slice 0..15 (32 cols)
  const int g0   = grp * 8;

  // ---- pin weight slice in registers: Bf[kk][j], j -> (gate, col-tile) ----
  short8 Bf[5][4];
#pragma unroll
  for (int kk = 0; kk < 5; ++kk) {
#pragma unroll
    for (int j = 0; j < 4; ++j) {
      int gate = cg * 2 + (j >> 1);
      int col = gate * HID + hw * 32 + (j & 1) * 16 + m;
      int k = kw * 160 + kk * 32 + q * 8;
      Bf[kk][j] = *(const short8*)(Wt + (size_t)col * 640 + k);
    }
  }

  // gate-thread state: tid<256 owns (row=tid>>5, col=tid&31)
  const int row = tid >> 5;
  const int col = tid & 31;
  const int hcol = hw * 32 + col;
  float c_state = 0.0f;
  float b_i = 0, b_f = 0, b_g = 0, b_o = 0;
  float2 wo = {0.f, 0.f};
  if (tid < 256) {
    b_i = bias[0 * HID + hcol];
    b_f = bias[1 * HID + hcol];
    b_g = bias[2 * HID + hcol];
    b_o = bias[3 * HID + hcol];
    wo = ((const float2*)Wo)[hcol];
  }

  const int arow = (m < 8) ? m : 7;   // clamp pad rows
  const int ab = g0 + arow;

#pragma unroll 1
  for (int t = 0; t < TLEN; ++t) {
    const unsigned* hin = hb + (size_t)(t & 1) * (BATCH * HID);

    // ---- A fragments: x region plain loads, h region tagged polls ----
    short8 a[5];
    unsigned long long wb[5][4];
#pragma unroll
    for (int kk = 0; kk < 5; ++kk) {
      int k = kw * 160 + kk * 32 + q * 8;
      if (k < 128) {
        a[kk] = *(const short8*)(xbf + ((size_t)ab * TLEN + t) * DIMX + k);
      } else {
        const unsigned* p = hin + ab * HID + (k - 128);
#pragma unroll
        for (int j = 0; j < 4; ++j) wb[kk][j] = aload64(p + j * 2);
      }
    }
    {
      unsigned long long rep = (unsigned)t;
      rep |= rep << 32;
      const unsigned long long MSK = 0x0000FFFF0000FFFFull;
      int guard = 0;
      for (;;) {
        bool all = true;
#pragma unroll
        for (int kk = 0; kk < 5; ++kk) {
          int k = kw * 160 + kk * 32 + q * 8;
          if (k >= 128) {
            unsigned long long d = (wb[kk][0] ^ rep) | (wb[kk][1] ^ rep) |
                                   (wb[kk][2] ^ rep) | (wb[kk][3] ^ rep);
            if ((d & MSK) != 0ull) {
              all = false;
              const unsigned* p = hin + ab * HID + (k - 128);
#pragma unroll
              for (int j = 0; j < 4; ++j) wb[kk][j] = aload64(p + j * 2);
            }
          }
        }
        if (all || ++guard > (1 << 20)) break;
      }
#pragma unroll
      for (int kk = 0; kk < 5; ++kk) {
        int k = kw * 160 + kk * 32 + q * 8;
        if (k >= 128) {
          union { short8 s; unsigned u[4]; } r;
#pragma unroll
          for (int j = 0; j < 4; ++j) {
            unsigned lo = (unsigned)wb[kk][j], hi = (unsigned)(wb[kk][j] >> 32);
            r.u[j] = (lo >> 16) | (hi & 0xFFFF0000u);
          }
          a[kk] = r.s;
        }
      }
    }

    // ---- MFMA: z partials for this wave's K-slice, gate pair ----
    f32x4 z0 = {0,0,0,0}, z1 = {0,0,0,0}, z2 = {0,0,0,0}, z3 = {0,0,0,0};
#pragma unroll
    for (int kk = 0; kk < 5; ++kk) {
      z0 = __builtin_amdgcn_mfma_f32_16x16x32_bf16(a[kk], Bf[kk][0], z0, 0, 0, 0);
      z1 = __builtin_amdgcn_mfma_f32_16x16x32_bf16(a[kk], Bf[kk][1], z1, 0, 0, 0);
      z2 = __builtin_amdgcn_mfma_f32_16x16x32_bf16(a[kk], Bf[kk][2], z2, 0, 0, 0);
      z3 = __builtin_amdgcn_mfma_f32_16x16x32_bf16(a[kk], Bf[kk][3], z3, 0, 0, 0);
    }

    // ---- stage partials (valid rows in quads 0,1), double-buffered ----
    const int buf = t & 1;
    if (q < 2) {
#pragma unroll
      for (int r = 0; r < 4; ++r) {
        int rw = q * 4 + r;
        red[buf][kw][cg * 2 + 0][rw][0 * 16 + m] = z0[r];
        red[buf][kw][cg * 2 + 0][rw][1 * 16 + m] = z1[r];
        red[buf][kw][cg * 2 + 1][rw][0 * 16 + m] = z2[r];
        red[buf][kw][cg * 2 + 1][rw][1 * 16 + m] = z3[r];
      }
    }
    __syncthreads();

    // ---- gates + state + tagged h store + logit duty (waves 0-3) ----
    if (tid < 256) {
      float zi = b_i + red[buf][0][0][row][col] + red[buf][1][0][row][col]
                     + red[buf][2][0][row][col] + red[buf][3][0][row][col];
      float zf = b_f + red[buf][0][1][row][col] + red[buf][1][1][row][col]
                     + red[buf][2][1][row][col] + red[buf][3][1][row][col];
      float zg = b_g + red[buf][0][2][row][col] + red[buf][1][2][row][col]
                     + red[buf][2][2][row][col] + red[buf][3][2][row][col];
      float zo = b_o + red[buf][0][3][row][col] + red[buf][1][3][row][col]
                     + red[buf][2][3][row][col] + red[buf][3][3][row][col];
      float ig = sigm(zi), fg = sigm(zf), gg = tanh_fast(zg), og = sigm(zo);
      c_state = fg * c_state + ig * gg;
      float hval = og * tanh_fast(c_state);

      unsigned hword = ((unsigned)f2bf(hval) << 16) | (unsigned)((t + 1) & 0xFFFF);
      __hip_atomic_store(hb + (size_t)((t + 1) & 1) * (BATCH * HID) +
                             (size_t)(g0 + row) * HID + hcol,
                         hword, __ATOMIC_RELAXED, __HIP_MEMORY_SCOPE_AGENT);

      // logit partials: sum over this WG's 32 cols via shuffle (lanes = cols)
      float p0 = hval * wo.x, p1 = hval * wo.y;
      p0 += __shfl_xor(p0, 16); p1 += __shfl_xor(p1, 16);
      p0 += __shfl_xor(p0, 8);  p1 += __shfl_xor(p1, 8);
      p0 += __shfl_xor(p0, 4);  p1 += __shfl_xor(p1, 4);
      p0 += __shfl_xor(p0, 2);  p1 += __shfl_xor(p1, 2);
      p0 += __shfl_xor(p0, 1);  p1 += __shfl_xor(p1, 1);
      if (col == 0) {
        float* po = out + ((size_t)(g0 + row) * TLEN + t) * 2;
        atomicAdd(po + 0, p0);
        atomicAdd(po + 1, p1);
      }
    }
  }
}

// ---- logits -> softmax probs + NLL ----
__global__ void k_out2(float* __restrict__ out, const float* __restrict__ bo,
                       const int* __restrict__ labels, float* __restrict__ acc) {
  __shared__ float sred[4];
  int i = blockIdx.x * 256 + threadIdx.x;   // 0..65535 = b*T + t
  float l0 = out[(size_t)i * 2 + 0] + bo[0];
  float l1 = out[(size_t)i * 2 + 1] + bo[1];
  float mx = fmaxf(l0, l1);
  float e0 = __expf(l0 - mx), e1 = __expf(l1 - mx);
  float s = e0 + e1, inv = 1.0f / s;
  out[(size_t)i * 2 + 0] = e0 * inv;
  out[(size_t)i * 2 + 1] = e1 * inv;
  int lab = labels[i];
  float nll = __logf(s) - ((lab ? l1 : l0) - mx);
#pragma unroll
  for (int off = 32; off >= 1; off >>= 1) nll += __shfl_xor(nll, off);
  if ((threadIdx.x & 63) == 0) sred[threadIdx.x >> 6] = nll;
  __syncthreads();
  if (threadIdx.x == 0)
    atomicAdd(acc, sred[0] + sred[1] + sred[2] + sred[3]);
}

__global__ void k_fin(const float* __restrict__ acc, float* __restrict__ out) {
  out[BATCH * TLEN * 2] = acc[0] * (1.0f / (float)(BATCH * TLEN));
}

extern "C" void kernel_launch(void* const* d_in, const int* in_sizes, int n_in,
                              void* d_out, int out_size, void* d_ws, size_t ws_size,
                              hipStream_t stream) {
  const float* x      = (const float*)d_in[0];
  const int*   labels = (const int*)d_in[1];
  const float* Wx     = (const float*)d_in[2];
  const float* Wh     = (const float*)d_in[3];
  const float* b      = (const float*)d_in[4];
  const float* Wo     = (const float*)d_in[5];
  const float* bo     = (const float*)d_in[6];
  float* out = (float*)d_out;
  char* ws = (char*)d_ws;

  unsigned short* Wt  = (unsigned short*)(ws + OFF_WT);
  unsigned short* xbf = (unsigned short*)(ws + OFF_XBF);
  unsigned*       hb  = (unsigned*)(ws + OFF_HB);
  float*          acc = (float*)(ws + OFF_ACC);

  // hb zero => h_0 = 0 with tag 0 (self-validating); acc zero; out zero (atomic target)
  hipMemsetAsync(ws + OFF_HB, 0, 262144 + 64, stream);
  hipMemsetAsync(d_out, 0, (size_t)BATCH * TLEN * 2 * sizeof(float), stream);
  k_convx<<<8192, 256, 0, stream>>>((const float4*)x, (ushort4*)xbf);
  k_tw<<<640, 256, 0, stream>>>(Wx, Wh, Wt);
  k_lstm<<<128, 512, 0, stream>>>(xbf, Wt, b, Wo, hb, out);
  k_out2<<<256, 256, 0, stream>>>(out, bo, labels, acc);
  k_fin<<<1, 1, 0, stream>>>(acc, out);
}